// Round 6
// baseline (155.535 us; speedup 1.0000x reference)
//
#include <hip/hip_runtime.h>

typedef float f32x4 __attribute__((ext_vector_type(4)));

#define MFMA8(a, b, c) __builtin_amdgcn_mfma_f32_16x16x32_fp8_fp8((long)(a), (long)(b), (c), 0, 0, 0)

__device__ __forceinline__ unsigned char f2fp8(float v) {
    int pk = __builtin_amdgcn_cvt_pk_fp8_f32(v, v, 0, false);
    return (unsigned char)(pk & 0xff);
}
__device__ __forceinline__ long packrow8(const float* p) {
    f32x4 a = *(const f32x4*)(p);
    f32x4 b = *(const f32x4*)(p + 4);
    int lo = __builtin_amdgcn_cvt_pk_fp8_f32(a.x, a.y, 0, false);
    lo = __builtin_amdgcn_cvt_pk_fp8_f32(a.z, a.w, lo, true);
    int hi = __builtin_amdgcn_cvt_pk_fp8_f32(b.x, b.y, 0, false);
    hi = __builtin_amdgcn_cvt_pk_fp8_f32(b.z, b.w, hi, true);
    return (long)(((unsigned long)(unsigned int)hi << 32) | (unsigned int)lo);
}
__device__ __forceinline__ int pack4(const float* p) {
    int v = __builtin_amdgcn_cvt_pk_fp8_f32(p[0], p[1], 0, false);
    return __builtin_amdgcn_cvt_pk_fp8_f32(p[2], p[3], v, true);
}

// ---------------- Kernel A: conv + K/V build + LN partial sums ----------------
// grid (16 mi-rows, 32 batches), 512 threads. K stored [b][m][64], V stored [b][d][256].
__global__ __launch_bounds__(512) void k_kvb2(
    const float* __restrict__ x, const float* __restrict__ Wdw, const float* __restrict__ bdw,
    const float* __restrict__ Wk, const float* __restrict__ bk,
    const float* __restrict__ Wv, const float* __restrict__ bv,
    unsigned char* __restrict__ Kg, unsigned char* __restrict__ Vg,
    float* __restrict__ part)
{
    __shared__ __align__(16) unsigned char Y[16 * 72];
    __shared__ float sm[16];
    const int mi = blockIdx.x, b = blockIdx.y;
    const int t = threadIdx.x, w = t >> 6, lane = t & 63;
    const int quad = lane >> 4, l = lane & 15;
    const float* xb = x + b * 262144;

    const int s2l = lane & 3, mjl = lane >> 2;
    float s = 0.f, ss = 0.f;
    #pragma unroll
    for (int ci = 0; ci < 8; ++ci) {
        int c = w * 8 + ci;
        float wd0 = Wdw[c * 16 + 0 + s2l];
        float wd1 = Wdw[c * 16 + 4 + s2l];
        float wd2 = Wdw[c * 16 + 8 + s2l];
        float wd3 = Wdw[c * 16 + 12 + s2l];
        const float* xr = xb + c * 4096 + mi * 256;
        float v0 = xr[lane], v1 = xr[64 + lane], v2 = xr[128 + lane], v3 = xr[192 + lane];
        s  += v0 + v1 + v2 + v3;
        ss += v0 * v0 + v1 * v1 + v2 * v2 + v3 * v3;
        float acc = v0 * wd0;
        acc = fmaf(v1, wd1, acc);
        acc = fmaf(v2, wd2, acc);
        acc = fmaf(v3, wd3, acc);
        acc += __shfl_xor(acc, 1);
        acc += __shfl_xor(acc, 2);
        if (s2l == 0) Y[mjl * 72 + c] = f2fp8(acc + bdw[c]);
    }
    #pragma unroll
    for (int off = 32; off > 0; off >>= 1) {
        s  += __shfl_down(s, off);
        ss += __shfl_down(ss, off);
    }
    if (lane == 0) { sm[w * 2] = s; sm[w * 2 + 1] = ss; }
    __syncthreads();
    if (t == 0) {
        float S = 0.f, SS = 0.f;
        #pragma unroll
        for (int i = 0; i < 8; ++i) { S += sm[i * 2]; SS += sm[i * 2 + 1]; }
        part[(b * 16 + mi) * 2]     = S;
        part[(b * 16 + mi) * 2 + 1] = SS;
    }

    long ya0 = *(const long*)(Y + l * 72 + quad * 8);
    long ya1 = *(const long*)(Y + l * 72 + 32 + quad * 8);
    if (w < 4) {
        int e4 = w;
        long f0 = packrow8(Wk + (e4 * 16 + l) * 64 + quad * 8);
        long f1 = packrow8(Wk + (e4 * 16 + l) * 64 + 32 + quad * 8);
        float bb = bk[e4 * 16 + l];
        f32x4 c = { bb, bb, bb, bb };
        c = MFMA8(ya0, f0, c);
        c = MFMA8(ya1, f1, c);
        unsigned char* kd = Kg + b * 16384 + (mi * 16 + quad * 4) * 64 + e4 * 16 + l;
        #pragma unroll
        for (int r = 0; r < 4; ++r) kd[r * 64] = f2fp8(c[r]);
    } else {
        int d4 = w - 4;
        long f0 = packrow8(Wv + (d4 * 16 + l) * 64 + quad * 8);
        long f1 = packrow8(Wv + (d4 * 16 + l) * 64 + 32 + quad * 8);
        f32x4 c = { bv[d4 * 16 + quad * 4 + 0], bv[d4 * 16 + quad * 4 + 1],
                    bv[d4 * 16 + quad * 4 + 2], bv[d4 * 16 + quad * 4 + 3] };
        c = MFMA8(f0, ya0, c);
        c = MFMA8(f1, ya1, c);
        unsigned char* vd = Vg + b * 16384 + (d4 * 16 + quad * 4) * 256 + mi * 16 + l;
        #pragma unroll
        for (int r = 0; r < 4; ++r) vd[r * 256] = f2fp8(c[r]);
    }
}

// ---------------- Kernel B: Wq/Wo fp8 pre-pack + Wq row-sums ----------------
// 1 block, 256 threads. No dependencies on other kernels.
__global__ void k_prep0(const float* __restrict__ Wq, const float* __restrict__ Wo,
                        float* __restrict__ swq,
                        unsigned char* __restrict__ Wq8, unsigned char* __restrict__ Wo8)
{
    int t = threadIdx.x;
    {
        float f[16];
        #pragma unroll
        for (int g = 0; g < 4; ++g) *(f32x4*)&f[g * 4] = *(const f32x4*)(Wq + t * 16 + g * 4);
        uint4 o;
        o.x = pack4(&f[0]); o.y = pack4(&f[4]); o.z = pack4(&f[8]); o.w = pack4(&f[12]);
        *(uint4*)(Wq8 + t * 16) = o;
    }
    {
        float f[16];
        #pragma unroll
        for (int g = 0; g < 4; ++g) *(f32x4*)&f[g * 4] = *(const f32x4*)(Wo + t * 16 + g * 4);
        uint4 o;
        o.x = pack4(&f[0]); o.y = pack4(&f[4]); o.z = pack4(&f[8]); o.w = pack4(&f[12]);
        *(uint4*)(Wo8 + t * 16) = o;
    }
    if (t < 64) {
        float s = 0.f;
        for (int c = 0; c < 64; ++c) s += Wq[t * 64 + c];
        swq[t] = s;
    }
}

// ---------------- Kernel C: Q generation for all tokens (fp8 MFMA) ----------------
// grid (16 segs, 32 batches), 512 threads; block = 256 tokens.
// Q = rstd*(x_raw . Wq^T) + (bq - rstd*mu*swq), stored fp8 [b][n][64].
__global__ __launch_bounds__(512) void k_qgen(
    const float* __restrict__ x, const float* __restrict__ part,
    const float* __restrict__ bq, const float* __restrict__ swq,
    const unsigned char* __restrict__ Wq8, unsigned char* __restrict__ Qg)
{
    __shared__ __align__(16) unsigned char XS[256 * 72];
    const int seg = blockIdx.x, b = blockIdx.y;
    const int t = threadIdx.x, w = t >> 6, lane = t & 63;
    const int quad = lane >> 4, l = lane & 15;

    float S = 0.f, SS = 0.f;
    #pragma unroll
    for (int k = 0; k < 16; ++k) {
        S  += part[(b * 16 + k) * 2];
        SS += part[(b * 16 + k) * 2 + 1];
    }
    const float inv = 1.0f / 262144.0f;
    const float mu = S * inv;
    const float rstd = rsqrtf(SS * inv - mu * mu + 1e-5f);

    const int nb = seg * 256;
    const float* xb = x + b * 262144;
    #pragma unroll
    for (int ci = 0; ci < 8; ++ci) {
        int c = w * 8 + ci;
        const float* xr = xb + c * 4096 + nb;
        #pragma unroll
        for (int j = 0; j < 4; ++j)
            XS[(j * 64 + lane) * 72 + c] = f2fp8(xr[j * 64 + lane]);
    }
    long wqF[8];
    float qe[4];
    #pragma unroll
    for (int et = 0; et < 4; ++et) {
        wqF[et * 2 + 0] = *(const long*)(Wq8 + (et * 16 + l) * 64 + quad * 8);
        wqF[et * 2 + 1] = *(const long*)(Wq8 + (et * 16 + l) * 64 + 32 + quad * 8);
        qe[et] = bq[et * 16 + l] - rstd * mu * swq[et * 16 + l];
    }
    __syncthreads();

    unsigned char* Qb = Qg + b * 262144 + nb * 64;
    #pragma unroll
    for (int i = 0; i < 2; ++i) {
        int rt = w * 2 + i;
        long xa0 = *(const long*)(XS + (rt * 16 + l) * 72 + quad * 8);
        long xa1 = *(const long*)(XS + (rt * 16 + l) * 72 + 32 + quad * 8);
        #pragma unroll
        for (int et = 0; et < 4; ++et) {
            f32x4 c = { 0, 0, 0, 0 };
            c = MFMA8(xa0, wqF[et * 2 + 0], c);
            c = MFMA8(xa1, wqF[et * 2 + 1], c);
            unsigned char* qd = Qb + (rt * 16 + quad * 4) * 64 + et * 16 + l;
            #pragma unroll
            for (int r = 0; r < 4; ++r) qd[r * 64] = f2fp8(fmaf(rstd, c[r], qe[et]));
        }
    }
}

// ---------------- Kernel D: per-tile attention (fp8 MFMA), 2 tiles/block ----------------
// grid (32 tile-pairs, 32 batches), 512 threads = 8 waves.
// LDS: Kf [256][80] @0 | Vt [64][272] @20480 | TS [64][72] @37888 | PS 8x[16][40] @42496
// total 47616 B -> 3 blocks/CU.
__global__ __launch_bounds__(512, 6) void k_attn4(
    const float* __restrict__ x, const unsigned char* __restrict__ Qg,
    const unsigned char* __restrict__ Wo8, const float* __restrict__ bo,
    const float* __restrict__ Bb, const unsigned char* __restrict__ Kg,
    const unsigned char* __restrict__ Vg, float* __restrict__ outp)
{
    __shared__ __align__(16) long smem8[5952];
    unsigned char* S = (unsigned char*)smem8;
    unsigned char* Kf = S;                 // [256][80]
    unsigned char* Vt = S + 20480;         // [64][272]
    unsigned char* TS = S + 37888;         // [64][72]
    const int tp = blockIdx.x, b = blockIdx.y;
    const int t = threadIdx.x, w = t >> 6, lane = t & 63;
    const int quad = lane >> 4, l = lane & 15;
    unsigned char* PS = S + 42496 + w * 640;
    const float* xb = x + b * 262144;
    const float SCALE = 0.17677669529663687f;

    // ---- stage K, V from ws (fp8) ----
    const unsigned char* Kgb = Kg + b * 16384;
    const unsigned char* Vgb = Vg + b * 16384;
    #pragma unroll
    for (int r = 0; r < 2; ++r) {
        int idx = t + 512 * r;
        int m = idx >> 2, c16 = (idx & 3) * 16;
        *(uint4*)(Kf + m * 80 + c16) = *(const uint4*)(Kgb + m * 64 + c16);
        int d = idx >> 4, e16 = (idx & 15) * 16;
        *(uint4*)(Vt + d * 272 + e16) = *(const uint4*)(Vgb + d * 256 + e16);
    }
    // ---- out-proj weight fragments ----
    const int rtq = w >> 1, ct0 = (w & 1) * 2;
    long woF[4];
    float bor[2];
    #pragma unroll
    for (int i = 0; i < 2; ++i) {
        woF[i * 2 + 0] = *(const long*)(Wo8 + ((ct0 + i) * 16 + l) * 64 + quad * 8);
        woF[i * 2 + 1] = *(const long*)(Wo8 + ((ct0 + i) * 16 + l) * 64 + 32 + quad * 8);
        bor[i] = bo[(ct0 + i) * 16 + l];
    }
    const int h = w & 1, nq = w >> 1;
    __syncthreads();

    for (int it = 0; it < 2; ++it) {
        const int tile = tp * 2 + it, n0 = tile * 64;
        long qa = *(const long*)(Qg + b * 262144 + (n0 + nq * 16 + l) * 64 + h * 32 + quad * 8);
        f32x4 O0 = { 0, 0, 0, 0 }, O1 = { 0, 0, 0, 0 };
        float Lp[4] = { 0, 0, 0, 0 };
        const float* Bbase = Bb + h * 1048576 + (n0 + nq * 16 + quad * 4) * 256;

        float Bv[2][4];
        #pragma unroll
        for (int sub = 0; sub < 2; ++sub)
            #pragma unroll
            for (int r = 0; r < 4; ++r)
                Bv[sub][r] = Bbase[r * 256 + sub * 16 + l];

        #pragma unroll 2
        for (int mc = 0; mc < 8; ++mc) {
            float Bn[2][4];
            if (mc < 7) {
                #pragma unroll
                for (int sub = 0; sub < 2; ++sub)
                    #pragma unroll
                    for (int r = 0; r < 4; ++r)
                        Bn[sub][r] = Bbase[r * 256 + (mc * 2 + 2 + sub) * 16 + l];
            }
            long kb0 = *(const long*)(Kf + ((mc * 2 + 0) * 16 + l) * 80 + h * 32 + quad * 8);
            long kb1 = *(const long*)(Kf + ((mc * 2 + 1) * 16 + l) * 80 + h * 32 + quad * 8);
            #pragma unroll
            for (int sub = 0; sub < 2; ++sub) {
                f32x4 sc = { 0, 0, 0, 0 };
                sc = MFMA8(qa, sub ? kb1 : kb0, sc);
                unsigned char* pw = PS + (quad * 4) * 40 + sub * 16 + l;
                #pragma unroll
                for (int r = 0; r < 4; ++r) {
                    float p = __expf(fmaf(sc[r], SCALE, Bv[sub][r]));
                    Lp[r] += p;
                    pw[r * 40] = f2fp8(p);
                }
            }
            long pa  = *(const long*)(PS + l * 40 + quad * 8);
            long vb0 = *(const long*)(Vt + (h * 32 + l) * 272 + mc * 32 + quad * 8);
            long vb1 = *(const long*)(Vt + (h * 32 + 16 + l) * 272 + mc * 32 + quad * 8);
            O0 = MFMA8(pa, vb0, O0);
            O1 = MFMA8(pa, vb1, O1);
            #pragma unroll
            for (int sub = 0; sub < 2; ++sub)
                #pragma unroll
                for (int r = 0; r < 4; ++r)
                    Bv[sub][r] = Bn[sub][r];
        }
        #pragma unroll
        for (int r = 0; r < 4; ++r) {
            #pragma unroll
            for (int d = 1; d < 16; d <<= 1) Lp[r] += __shfl_xor(Lp[r], d);
        }
        {
            unsigned char* td = TS + (nq * 16 + quad * 4) * 72 + h * 32 + l;
            #pragma unroll
            for (int r = 0; r < 4; ++r) {
                float inv = 1.0f / Lp[r];
                td[r * 72]      = f2fp8(O0[r] * inv);
                td[r * 72 + 16] = f2fp8(O1[r] * inv);
            }
        }
        __syncthreads();

        {
            long ta0 = *(const long*)(TS + (rtq * 16 + l) * 72 + quad * 8);
            long ta1 = *(const long*)(TS + (rtq * 16 + l) * 72 + 32 + quad * 8);
            float* ob = outp + b * 262144 + tile * 4096;
            const float* xr2 = xb + tile * 4096;
            #pragma unroll
            for (int i = 0; i < 2; ++i) {
                f32x4 c = { bor[i], bor[i], bor[i], bor[i] };
                c = MFMA8(ta0, woF[i * 2 + 0], c);
                c = MFMA8(ta1, woF[i * 2 + 1], c);
                #pragma unroll
                for (int r = 0; r < 4; ++r) {
                    int off = (rtq * 16 + quad * 4 + r) * 64 + (ct0 + i) * 16 + l;
                    ob[off] = c[r] + xr2[off];
                }
            }
        }
        __syncthreads();
    }
}

extern "C" void kernel_launch(void* const* d_in, const int* in_sizes, int n_in,
                              void* d_out, int out_size, void* d_ws, size_t ws_size,
                              hipStream_t stream) {
    (void)in_sizes; (void)n_in; (void)out_size; (void)ws_size;
    const float* x   = (const float*)d_in[0];
    const float* Wdw = (const float*)d_in[1];
    const float* bdw = (const float*)d_in[2];
    const float* Wq  = (const float*)d_in[3];
    const float* bq  = (const float*)d_in[4];
    const float* Wk  = (const float*)d_in[5];
    const float* bk  = (const float*)d_in[6];
    const float* Wv  = (const float*)d_in[7];
    const float* bv  = (const float*)d_in[8];
    const float* Wo  = (const float*)d_in[9];
    const float* bo  = (const float*)d_in[10];
    const float* Bb  = (const float*)d_in[11];
    float* outp = (float*)d_out;

    float* part = (float*)d_ws;                            // 1024 f32 @ 0
    float* swq  = (float*)((char*)d_ws + 4096);            // 64 f32
    unsigned char* Wq8 = (unsigned char*)d_ws + 8192;      // 4 KB
    unsigned char* Wo8 = (unsigned char*)d_ws + 12288;     // 4 KB
    unsigned char* Kg  = (unsigned char*)d_ws + 16384;     // 512 KB
    unsigned char* Vg  = Kg + 524288;                      // 512 KB
    unsigned char* Qg  = Vg + 524288;                      // 8 MB  (total ~9.1 MB of 256 MiB ws)

    k_kvb2<<<dim3(16, 32), 512, 0, stream>>>(x, Wdw, bdw, Wk, bk, Wv, bv, Kg, Vg, part);
    k_prep0<<<1, 256, 0, stream>>>(Wq, Wo, swq, Wq8, Wo8);
    k_qgen<<<dim3(16, 32), 512, 0, stream>>>(x, part, bq, swq, Wq8, Qg);
    k_attn4<<<dim3(32, 32), 512, 0, stream>>>(x, Qg, Wo8, bo, Bb, Kg, Vg, outp);
}